// Round 11
// baseline (119.591 us; speedup 1.0000x reference)
//
#include <hip/hip_runtime.h>
#include <hip/hip_bf16.h>
#include <stdint.h>

#define M_DIM 8192
#define N_DIM 1024
#define K_DIM 4096

typedef __bf16 bf16x8 __attribute__((ext_vector_type(8)));
typedef float f32x16 __attribute__((ext_vector_type(16)));
typedef __hip_bfloat16 bf16_t;

__device__ __forceinline__ void gload_lds16(const void* g, void* l) {
  __builtin_amdgcn_global_load_lds(
      (const __attribute__((address_space(1))) void*)g,
      (__attribute__((address_space(3))) void*)l, 16, 0, 0);
}

__device__ __forceinline__ float b2f(unsigned short u) {
  union { unsigned i; float f; } x;
  x.i = ((unsigned)u) << 16;
  return x.f;
}

// ---- pack: fp32 [R][4096] -> bf16 tiled [rt][kt][256 rows][8 chunks], with
// st-swizzle pre-applied (chunk' = chunk ^ (row&7)); enc+W in one launch.
__global__ __launch_bounds__(256) void pack_both(const float* __restrict__ enc,
                                                 const float* __restrict__ W,
                                                 int4* __restrict__ pA,
                                                 int4* __restrict__ pB) {
  const unsigned gtid = blockIdx.x * 256 + threadIdx.x;
  const float* src;
  int4* dst;
  unsigned t;
  if (gtid < 4194304u) { src = enc; dst = pA; t = gtid; }          // 8192*4096/8
  else                 { src = W;   dst = pB; t = gtid - 4194304u; }
  const unsigned cp = t & 7;
  const unsigned tmp = t >> 3;
  const unsigned r = tmp & 255;
  const unsigned tmp2 = tmp >> 8;
  const unsigned kt = tmp2 & 63;
  const unsigned rt = tmp2 >> 6;
  const unsigned srow = (rt << 8) + r;
  const unsigned k0 = (kt << 6) + ((cp ^ (r & 7)) << 3);
  const float4* s = (const float4*)(src + (size_t)srow * 4096 + k0);
  float4 a = s[0], b = s[1];
  union { bf16_t h[8]; int4 v; } u;
  u.h[0] = __float2bfloat16(a.x); u.h[1] = __float2bfloat16(a.y);
  u.h[2] = __float2bfloat16(a.z); u.h[3] = __float2bfloat16(a.w);
  u.h[4] = __float2bfloat16(b.x); u.h[5] = __float2bfloat16(b.y);
  u.h[6] = __float2bfloat16(b.z); u.h[7] = __float2bfloat16(b.w);
  dst[t] = u.v;
}

// ---- 8-phase 256x256 GEMM: r10 schedule, 32x32x16 MFMA (r11) -----------------
// 512 thr = 8 waves (2M x 4N), per-wave C = 128x64 as 4 M-frags x 2 N-frags of
// 32x32. Same LDS layout / stage calls / vmcnt ledger / phase order as r10:
//   P0: stage Bh0/Bh1(g+1); MFMA M0N0; tail read b1(g);  vmcnt(6)
//   P1: stage Ah1(g+1);     MFMA M0N1; tail read aO(g);  no wait
//   P2: stage Ah0(g+2);     MFMA M1N1; vmcnt(8); tail read aE(g+1)
//   P3:                     MFMA M1N0; vmcnt(4); tail read b0(g+1)
// 32x32x16 lane layout: A/B lane l holds [row=l&31][k=(l>>5)*8 + 0..7] -> same
// 16B-chunk reads from the same swizzled layout (chunk = (ks*2+(l>>5)) ^
// (row&7)).  C/D: col=lane&31, row=(reg&3)+8*(reg>>2)+4*(lane>>5) (m74/m101).
__device__ __forceinline__ void stage_half(const char* g, char* smem, int ldsoff, int tid) {
  gload_lds16(g + tid * 16, smem + ldsoff + tid * 16);
  gload_lds16(g + 8192 + tid * 16, smem + ldsoff + 8192 + tid * 16);
}

__global__ __launch_bounds__(512, 2) void gemm8(
    const char* __restrict__ pA, const char* __restrict__ pB,
    bf16_t* __restrict__ V0, bf16_t* __restrict__ V1p, int NT) {
  extern __shared__ char smem[];
  const int tid = threadIdx.x;
  const int lane = tid & 63, wave = tid >> 6;
  const int wm = wave >> 2, wn = wave & 3;
  const int l31 = lane & 31, lkg = lane >> 5;

  // XCD-aware swizzle (grid 128/256 -> %8==0, bijective)
  const int cpx = (int)gridDim.x >> 3;
  const int swz = ((int)blockIdx.x & 7) * cpx + ((int)blockIdx.x >> 3);
  const int split = swz >> 7;
  const int rem = swz & 127;
  const int mt = rem >> 2, nt = rem & 3;

  const char* Abase = pA + ((size_t)mt * 64 + (size_t)split * NT) * 32768;
  const char* Bbase = pB + ((size_t)nt * 64 + (size_t)split * NT) * 32768;
  bf16_t* V = split ? V1p : V0;

  // Per-lane swizzled k-chunk offsets: chunk = (ks*2 + lkg) ^ (row&7),
  // row&7 == lane&7 for every fragment row (other terms are multiples of 8).
  int colw[4];
  #pragma unroll
  for (int ks = 0; ks < 4; ++ks)
    colw[ks] = (((ks * 2 + lkg) ^ (lane & 7)) << 4);
  // A frag rows: f in {0,1} within a half-tile; M0 in Ah0, M1 in Ah1.
  int aRow[2];
  #pragma unroll
  for (int f = 0; f < 2; ++f) aRow[f] = (wm * 64 + f * 32 + l31) * 128;
  // B frag row (one 32-col frag per half-tile): wn*32 + l31.
  const int bRow = 32768 + (wn * 32 + l31) * 128;

  f32x16 acc[4][2];
  #pragma unroll
  for (int f = 0; f < 4; ++f)
    #pragma unroll
    for (int n = 0; n < 2; ++n)
      #pragma unroll
      for (int r = 0; r < 16; ++r)
        acc[f][n][r] = 0.f;

  const int ktm = NT - 1;

  // ---- Prologue: stage tile-0 (Ah0,Bh0,Bh1 first, then Ah1) + Ah0(1);
  // vmcnt(4) retires the first three -> entry invariant [Ah1(0)2, Ah0(1)2].
  stage_half(Abase,         smem, 0, tid);       // Ah0(0)
  stage_half(Bbase,         smem, 32768, tid);   // Bh0(0)
  stage_half(Bbase + 16384, smem, 49152, tid);   // Bh1(0)
  stage_half(Abase + 16384, smem, 16384, tid);   // Ah1(0)
  stage_half(Abase + 32768, smem, 65536, tid);   // Ah0(1)
  asm volatile("s_waitcnt vmcnt(4)" ::: "memory");
  __builtin_amdgcn_sched_barrier(0);
  __builtin_amdgcn_s_barrier();

  bf16x8 aE[2][4], aO[2][4], b0[4], b1[4];
  #pragma unroll
  for (int f = 0; f < 2; ++f)
    #pragma unroll
    for (int ks = 0; ks < 4; ++ks)
      aE[f][ks] = *(const bf16x8*)(smem + aRow[f] + colw[ks]);
  #pragma unroll
  for (int ks = 0; ks < 4; ++ks)
    b0[ks] = *(const bf16x8*)(smem + bRow + colw[ks]);

  for (int g = 0; g < NT; ++g) {
    const int bb = g & 1, nbf = bb ^ 1;
    char* ab = smem + bb * 65536;
    char* nb = smem + nbf * 65536;
    const char* A1t = Abase + (size_t)((g + 1) & ktm) * 32768;
    const char* B1t = Bbase + (size_t)((g + 1) & ktm) * 32768;
    const char* A2t = Abase + (size_t)((g + 2) & ktm) * 32768;

    // ---- P0: stage Bh0/Bh1(g+1); MFMA M0N0; tail read b1(g); vmcnt(6) ------
    stage_half(B1t, smem, nbf * 65536 + 32768, tid);          // Bh0(g+1)
    stage_half(B1t + 16384, smem, nbf * 65536 + 49152, tid);  // Bh1(g+1)
    __builtin_amdgcn_s_setprio(1);
    #pragma unroll
    for (int f = 0; f < 2; ++f)
      #pragma unroll
      for (int ks = 0; ks < 4; ++ks)
        acc[f][0] = __builtin_amdgcn_mfma_f32_32x32x16_bf16(
            aE[f][ks], b0[ks], acc[f][0], 0, 0, 0);
    __builtin_amdgcn_s_setprio(0);
    __builtin_amdgcn_sched_barrier(0);
    #pragma unroll
    for (int ks = 0; ks < 4; ++ks)
      b1[ks] = *(const bf16x8*)(ab + bRow + 16384 + colw[ks]);
    asm volatile("s_waitcnt vmcnt(6)" ::: "memory");
    __builtin_amdgcn_sched_barrier(0);
    __builtin_amdgcn_s_barrier();

    // ---- P1: stage Ah1(g+1); MFMA M0N1; tail read aO(g) --------------------
    stage_half(A1t + 16384, smem, nbf * 65536 + 16384, tid);  // Ah1(g+1)
    __builtin_amdgcn_s_setprio(1);
    #pragma unroll
    for (int f = 0; f < 2; ++f)
      #pragma unroll
      for (int ks = 0; ks < 4; ++ks)
        acc[f][1] = __builtin_amdgcn_mfma_f32_32x32x16_bf16(
            aE[f][ks], b1[ks], acc[f][1], 0, 0, 0);
    __builtin_amdgcn_s_setprio(0);
    __builtin_amdgcn_sched_barrier(0);
    #pragma unroll
    for (int f = 0; f < 2; ++f)
      #pragma unroll
      for (int ks = 0; ks < 4; ++ks)
        aO[f][ks] = *(const bf16x8*)(ab + aRow[f] + 16384 + colw[ks]);
    __builtin_amdgcn_sched_barrier(0);
    __builtin_amdgcn_s_barrier();

    // ---- P2: stage Ah0(g+2); MFMA M1N1; vmcnt(8); tail read aE(g+1) --------
    stage_half(A2t, smem, bb * 65536, tid);                   // Ah0(g+2)
    __builtin_amdgcn_s_setprio(1);
    #pragma unroll
    for (int f = 0; f < 2; ++f)
      #pragma unroll
      for (int ks = 0; ks < 4; ++ks)
        acc[2 + f][1] = __builtin_amdgcn_mfma_f32_32x32x16_bf16(
            aO[f][ks], b1[ks], acc[2 + f][1], 0, 0, 0);
    __builtin_amdgcn_s_setprio(0);
    __builtin_amdgcn_sched_barrier(0);
    asm volatile("s_waitcnt vmcnt(8)" ::: "memory");
    #pragma unroll
    for (int f = 0; f < 2; ++f)
      #pragma unroll
      for (int ks = 0; ks < 4; ++ks)
        aE[f][ks] = *(const bf16x8*)(nb + aRow[f] + colw[ks]);
    __builtin_amdgcn_sched_barrier(0);
    __builtin_amdgcn_s_barrier();

    // ---- P3: MFMA M1N0; vmcnt(4); tail read b0(g+1) ------------------------
    __builtin_amdgcn_s_setprio(1);
    #pragma unroll
    for (int f = 0; f < 2; ++f)
      #pragma unroll
      for (int ks = 0; ks < 4; ++ks)
        acc[2 + f][0] = __builtin_amdgcn_mfma_f32_32x32x16_bf16(
            aO[f][ks], b0[ks], acc[2 + f][0], 0, 0, 0);
    __builtin_amdgcn_s_setprio(0);
    __builtin_amdgcn_sched_barrier(0);
    asm volatile("s_waitcnt vmcnt(4)" ::: "memory");
    #pragma unroll
    for (int ks = 0; ks < 4; ++ks)
      b0[ks] = *(const bf16x8*)(nb + bRow + colw[ks]);
    __builtin_amdgcn_sched_barrier(0);
    __builtin_amdgcn_s_barrier();
  }

  // C-write (bf16 partials). 32x32 frag: col=lane&31,
  // row=(reg&3)+8*(reg>>2)+4*(lane>>5)  [m74/m101-verified].
  #pragma unroll
  for (int f = 0; f < 4; ++f) {
    const int mhalf = f >> 1;                 // 0: rows in Ah0 range, 1: Ah1
    const int rbase = mt * 256 + mhalf * 128 + wm * 64 + (f & 1) * 32 + lkg * 4;
    #pragma unroll
    for (int n = 0; n < 2; ++n) {
      const int colg = nt * 256 + n * 128 + wn * 32 + l31;
      #pragma unroll
      for (int reg = 0; reg < 16; ++reg) {
        const int rowg = rbase + (reg & 3) + 8 * (reg >> 2);
        V[(size_t)rowg * N_DIM + colg] = __float2bfloat16(acc[f][n][reg]);
      }
    }
  }
}

// ---- Householder epilogue: combine bf16 split-K partials, write f32 out ------
__global__ __launch_bounds__(256) void householder_ep(
    const float* __restrict__ x, const float* __restrict__ bias,
    const unsigned short* __restrict__ V0b, const unsigned short* __restrict__ V1b,
    float* __restrict__ out, float* __restrict__ logdet) {
  const int row = blockIdx.x;
  const int t = threadIdx.x;
  const float4* xr = (const float4*)(x + (size_t)row * N_DIM);
  const float4* br = (const float4*)bias;

  ushort4 u0 = ((const ushort4*)(V0b + (size_t)row * N_DIM))[t];
  float4 v;
  v.x = b2f(u0.x); v.y = b2f(u0.y); v.z = b2f(u0.z); v.w = b2f(u0.w);
  if (V1b) {
    ushort4 u1 = ((const ushort4*)(V1b + (size_t)row * N_DIM))[t];
    v.x += b2f(u1.x); v.y += b2f(u1.y); v.z += b2f(u1.z); v.w += b2f(u1.w);
  }
  float4 bb = br[t];
  v.x += bb.x; v.y += bb.y; v.z += bb.z; v.w += bb.w;
  float4 xx = xr[t];

  float dot = v.x * xx.x + v.y * xx.y + v.z * xx.z + v.w * xx.w;
  float nsq = v.x * v.x + v.y * v.y + v.z * v.z + v.w * v.w;

  #pragma unroll
  for (int off = 32; off > 0; off >>= 1) {
    dot += __shfl_down(dot, off);
    nsq += __shfl_down(nsq, off);
  }
  __shared__ float sd[4], sn[4];
  if ((t & 63) == 0) { sd[t >> 6] = dot; sn[t >> 6] = nsq; }
  __syncthreads();
  dot = sd[0] + sd[1] + sd[2] + sd[3];
  nsq = sn[0] + sn[1] + sn[2] + sn[3];

  const float f = 2.0f * dot / sqrtf(nsq);
  float4 o;
  o.x = xx.x - f * v.x;
  o.y = xx.y - f * v.y;
  o.z = xx.z - f * v.z;
  o.w = xx.w - f * v.w;
  ((float4*)(out + (size_t)row * N_DIM))[t] = o;
  if (t == 0) logdet[row] = 0.0f;
}

extern "C" void kernel_launch(void* const* d_in, const int* in_sizes, int n_in,
                              void* d_out, int out_size, void* d_ws, size_t ws_size,
                              hipStream_t stream) {
  const float* x   = (const float*)d_in[0];   // [8192,1024]
  const float* enc = (const float*)d_in[1];   // [8192,4096]
  const float* W   = (const float*)d_in[2];   // [1024,4096]
  const float* b   = (const float*)d_in[3];   // [1024]

  float* out    = (float*)d_out;
  float* logdet = out + (size_t)M_DIM * N_DIM;

  char*   packA = (char*)d_ws;                              // 64 MB
  char*   packB = packA + (size_t)64 * 1024 * 1024;         //  8 MB
  bf16_t* V0b   = (bf16_t*)(packB + (size_t)8 * 1024 * 1024);   // 16 MB
  bf16_t* V1b   = V0b + (size_t)M_DIM * N_DIM;                  // 16 MB

  const size_t need2 = (size_t)104 * 1024 * 1024;
  const int nsplit = (ws_size >= need2) ? 2 : 1;

  pack_both<<<18432, 256, 0, stream>>>(enc, W, (int4*)packA, (int4*)packB);

  hipFuncSetAttribute((const void*)gemm8, hipFuncAttributeMaxDynamicSharedMemorySize, 131072);
  gemm8<<<dim3(128 * nsplit), 512, 131072, stream>>>(
      packA, packB, V0b, nsplit == 2 ? V1b : nullptr, 64 / nsplit);

  householder_ep<<<M_DIM, 256, 0, stream>>>(
      x, b, (const unsigned short*)V0b,
      nsplit == 2 ? (const unsigned short*)V1b : nullptr, out, logdet);
}